// Round 9
// baseline (811.895 us; speedup 1.0000x reference)
//
#include <hip/hip_runtime.h>
#include <hip/hip_bf16.h>
#include <math.h>

typedef _Float16 f16;
typedef _Float16 f16x4 __attribute__((ext_vector_type(4)));
typedef _Float16 f16x8 __attribute__((ext_vector_type(8)));
typedef float f32x16 __attribute__((ext_vector_type(16)));

constexpr int CH = 8;      // channels
constexpr int TT = 2048;   // time frames
constexpr int FB = 257;    // freq bins
constexpr int HD = 256;    // hidden
constexpr int DHD = 64;    // head dim
constexpr int WN = 512;    // ffn dim
constexpr int HF = 128;    // H/2
constexpr int RR = 8 * TT; // 16384 rows
constexpr int KXP = 288;   // padded K for x / W_in

// acc += (Ah+Al)*(Bh+Bl) to ~2^-22 rel: acc = Al*Bh + Ah*Bl + Ah*Bh
#define MFMA3(ACCV, AH, AL, BH, BL)                                            \
  ACCV = __builtin_amdgcn_mfma_f32_32x32x16_f16(AL, BH, ACCV, 0, 0, 0);        \
  ACCV = __builtin_amdgcn_mfma_f32_32x32x16_f16(AH, BL, ACCV, 0, 0, 0);        \
  ACCV = __builtin_amdgcn_mfma_f32_32x32x16_f16(AH, BH, ACCV, 0, 0, 0);

// ---------------------------------------------------------------------------
// gemm2 (final W_out GEMM only): tile 128x64, 4 waves. (R5-verified)
// ---------------------------------------------------------------------------
template<int ACT>
__global__ __launch_bounds__(256, 2) void gemm2(
    const f16* __restrict__ Ahi, const f16* __restrict__ Alo, int K,
    const f16* __restrict__ Bp, const float* __restrict__ bias,
    float* __restrict__ C0, int ldc, int Nreal)
{
  __shared__ f16 As[2][2][128][40];
  const int tid = threadIdx.x;
  const int m0 = blockIdx.x * 128;
  const int n0 = blockIdx.y * 64;
  const int q = tid & 3, r = tid >> 2;
  const int lane = tid & 63, wm = tid >> 6;
  const int lr = lane & 31, lg = lane >> 5;
  const int nb0 = n0 >> 5, kd8 = K >> 3;

  f32x16 acc[2];
  #pragma unroll
  for (int nf = 0; nf < 2; nf++)
    #pragma unroll
    for (int g = 0; g < 16; g++) acc[nf][g] = 0.f;

  const long aoff = (long)(m0 + r) * K + q * 8;
  const long hstep = (long)64 * K;
  f16x8 sA[4];
  auto loadA = [&](int k0) {
    const long a = aoff + k0;
    sA[0] = *(const f16x8*)(Ahi + a);  sA[1] = *(const f16x8*)(Ahi + a + hstep);
    sA[2] = *(const f16x8*)(Alo + a);  sA[3] = *(const f16x8*)(Alo + a + hstep);
  };
  auto loadB = [&](f16x8 B[2][2][2], int k0) {
    const int kb = (k0 >> 3) + lg;
    #pragma unroll
    for (int kh = 0; kh < 2; kh++)
      #pragma unroll
      for (int nf = 0; nf < 2; nf++)
        #pragma unroll
        for (int hl = 0; hl < 2; hl++)
          B[kh][nf][hl] = *(const f16x8*)(Bp +
              ((long)((nb0 + nf) * kd8 + kb + kh * 2) * 512 + hl * 256 + lr * 8));
  };
  auto kstep = [&](f16x8 SB[2][2][2], f16x8 TB[2][2][2], int k0, int d) {
    *(f16x8*)&As[d][0][r][q * 8]      = sA[0];
    *(f16x8*)&As[d][0][r + 64][q * 8] = sA[1];
    *(f16x8*)&As[d][1][r][q * 8]      = sA[2];
    *(f16x8*)&As[d][1][r + 64][q * 8] = sA[3];
    __syncthreads();
    if (k0 + 32 < K) { loadA(k0 + 32); loadB(TB, k0 + 32); }
    f16x8 fa[2][2];
    #pragma unroll
    for (int kh = 0; kh < 2; kh++)
      #pragma unroll
      for (int hl = 0; hl < 2; hl++)
        fa[kh][hl] = *(const f16x8*)&As[d][hl][wm * 32 + lr][kh * 16 + lg * 8];
    #pragma unroll
    for (int kh = 0; kh < 2; kh++)
      #pragma unroll
      for (int nf = 0; nf < 2; nf++) {
        MFMA3(acc[nf], fa[kh][0], fa[kh][1], SB[kh][nf][0], SB[kh][nf][1]);
      }
  };

  f16x8 B0[2][2][2], B1[2][2][2];
  loadA(0);
  loadB(B0, 0);
  int d = 0;
  for (int k0 = 0; k0 < K; k0 += 64) {
    kstep(B0, B1, k0, d); d ^= 1;
    if (k0 + 32 < K) { kstep(B1, B0, k0 + 32, d); d ^= 1; }
  }

  #pragma unroll
  for (int nf = 0; nf < 2; nf++) {
    const int col = n0 + nf * 32 + lr;
    const float bb = (col < Nreal) ? bias[col] : 0.f;
    #pragma unroll
    for (int g = 0; g < 16; g++) {
      const long row = m0 + wm * 32 + (g & 3) + 8 * (g >> 2) + 4 * lg;
      float v = acc[nf][g] + bb;
      if (ACT) v = fmaxf(v, 0.f);
      if (col < Nreal) C0[row * (long)ldc + col] = v;
    }
  }
}

// ---------------------------------------------------------------------------
// FUSED lin1 + QKV (R8-verified, unchanged).
// ---------------------------------------------------------------------------
__global__ __launch_bounds__(512) void lin1_qkv(
    const float* __restrict__ x, long agrp,
    const f16* __restrict__ WinP, const float* __restrict__ b_in,
    const f16* __restrict__ WqkvP, const float* __restrict__ bq,
    const float* __restrict__ bk, const float* __restrict__ bv,
    f16* __restrict__ lin1hi, f16* __restrict__ lin1lo,
    float* __restrict__ Qb, float* __restrict__ Ksd, float* __restrict__ Vsd,
    const int* __restrict__ alive)
{
  if (alive && *alive == 0) return;
  __shared__ f16 As[2][2][64][40];
  __shared__ f16 L1[2][64][264];
  const int tid = threadIdx.x;
  const int m0 = blockIdx.x * 64;
  const int lane = tid & 63, wave = tid >> 6;
  const int wm = wave & 1, wn = wave >> 1;
  const int lr = lane & 31, lg = lane >> 5;
  const int srow = tid >> 3, sk = (tid & 7) * 4;

  const int r0 = m0 + srow;
  const float* xrow = x + (long)(r0 >> 11) * agrp + (long)(r0 & 2047) * FB;

  f16x4 sAh, sAl;
  auto loadA = [&](int k0) {
    float v[4];
    #pragma unroll
    for (int j = 0; j < 4; j++) {
      const int k = k0 + sk + j;
      v[j] = (k < FB) ? xrow[k] : 0.f;
    }
    #pragma unroll
    for (int j = 0; j < 4; j++) {
      const f16 h = (f16)v[j];
      sAh[j] = h; sAl[j] = (f16)(v[j] - (float)h);
    }
  };
  auto loadB1 = [&](f16x8 B[2][2][2], int k0) {
    const int kb = (k0 >> 3) + lg;
    #pragma unroll
    for (int kh = 0; kh < 2; kh++)
      #pragma unroll
      for (int nf = 0; nf < 2; nf++)
        #pragma unroll
        for (int hl = 0; hl < 2; hl++)
          B[kh][nf][hl] = *(const f16x8*)(WinP +
              ((long)((wn * 2 + nf) * 36 + kb + kh * 2) * 512 + hl * 256 + lr * 8));
  };

  f32x16 acc[2];
  #pragma unroll
  for (int nf = 0; nf < 2; nf++)
    #pragma unroll
    for (int g = 0; g < 16; g++) acc[nf][g] = 0.f;

  auto kstep1 = [&](f16x8 SB[2][2][2], f16x8 TB[2][2][2], int k0, int d) {
    *(f16x4*)&As[d][0][srow][sk] = sAh;
    *(f16x4*)&As[d][1][srow][sk] = sAl;
    __syncthreads();
    if (k0 + 32 < KXP) { loadA(k0 + 32); loadB1(TB, k0 + 32); }
    f16x8 fa[2][2];
    #pragma unroll
    for (int kh = 0; kh < 2; kh++)
      #pragma unroll
      for (int hl = 0; hl < 2; hl++)
        fa[kh][hl] = *(const f16x8*)&As[d][hl][wm * 32 + lr][kh * 16 + lg * 8];
    #pragma unroll
    for (int kh = 0; kh < 2; kh++)
      #pragma unroll
      for (int nf = 0; nf < 2; nf++) {
        MFMA3(acc[nf], fa[kh][0], fa[kh][1], SB[kh][nf][0], SB[kh][nf][1]);
      }
  };

  f16x8 B0[2][2][2], B1[2][2][2];
  loadA(0);
  loadB1(B0, 0);
  #pragma unroll
  for (int s = 0; s < 9; s++) {
    if ((s & 1) == 0) kstep1(B0, B1, s * 32, 0);
    else              kstep1(B1, B0, s * 32, 1);
  }

  #pragma unroll
  for (int nf = 0; nf < 2; nf++) {
    const int col = wn * 64 + nf * 32 + lr;
    const float bb = b_in[col];
    #pragma unroll
    for (int g = 0; g < 16; g++) {
      const int row_l = wm * 32 + (g & 3) + 8 * (g >> 2) + 4 * lg;
      const float v = fmaxf(acc[nf][g] + bb, 0.f);
      const f16 hi = (f16)v;
      const f16 lo = (f16)(v - (float)hi);
      L1[0][row_l][col] = hi;
      L1[1][row_l][col] = lo;
      const long gi = (long)(m0 + row_l) * HD + col;
      lin1hi[gi] = hi;
      lin1lo[gi] = lo;
    }
  }
  __syncthreads();

  auto loadB2 = [&](f16x8 B[2][2][2], int k0, int sel) {
    const int kb = (k0 >> 3) + lg;
    #pragma unroll
    for (int kh = 0; kh < 2; kh++)
      #pragma unroll
      for (int nf = 0; nf < 2; nf++)
        #pragma unroll
        for (int hl = 0; hl < 2; hl++)
          B[kh][nf][hl] = *(const f16x8*)(WqkvP +
              ((long)((sel * 8 + wn * 2 + nf) * 32 + kb + kh * 2) * 512 + hl * 256 + lr * 8));
  };
  #pragma unroll
  for (int sel = 0; sel < 3; sel++) {
    f32x16 a2[2];
    #pragma unroll
    for (int nf = 0; nf < 2; nf++)
      #pragma unroll
      for (int g = 0; g < 16; g++) a2[nf][g] = 0.f;
    f16x8 Bc[2][2][2], Bn[2][2][2];
    loadB2(Bc, 0, sel);
    #pragma unroll
    for (int s = 0; s < 8; s++) {
      const int k0 = s * 32;
      if (s < 7) loadB2((s & 1) ? Bc : Bn, k0 + 32, sel);
      f16x8 fa[2][2];
      #pragma unroll
      for (int kh = 0; kh < 2; kh++)
        #pragma unroll
        for (int hl = 0; hl < 2; hl++)
          fa[kh][hl] = *(const f16x8*)&L1[hl][wm * 32 + lr][k0 + kh * 16 + lg * 8];
      #pragma unroll
      for (int kh = 0; kh < 2; kh++)
        #pragma unroll
        for (int nf = 0; nf < 2; nf++) {
          if (s & 1) { MFMA3(a2[nf], fa[kh][0], fa[kh][1], Bn[kh][nf][0], Bn[kh][nf][1]); }
          else       { MFMA3(a2[nf], fa[kh][0], fa[kh][1], Bc[kh][nf][0], Bc[kh][nf][1]); }
        }
    }
    float* dst = sel == 0 ? Qb : (sel == 1 ? Ksd : Vsd);
    const float* bp = sel == 0 ? bq : (sel == 1 ? bk : bv);
    #pragma unroll
    for (int nf = 0; nf < 2; nf++) {
      const int col = wn * 64 + nf * 32 + lr;
      const float bb = bp[col];
      #pragma unroll
      for (int g = 0; g < 16; g++) {
        const int row_l = wm * 32 + (g & 3) + 8 * (g >> 2) + 4 * lg;
        dst[(long)(m0 + row_l) * HD + col] = a2[nf][g] + bb;
      }
    }
  }
}

// ---------------------------------------------------------------------------
// FUSED attn + Wo GEMM + LN1: per 64-row block:
//   phase 1: ctx (attn over channels 0..NCc-1) -> LDS hi/lo (math == attn_k)
//   phase 2: h1 = LN(lin1 + ctx @ Wo + bo)     (structure == gemm_ln)
// 512 thr = 8 waves; attn: wave = (rowgrp, head); GEMM: 2 wm x 4 wn.
// ---------------------------------------------------------------------------
template<int NCc>
__global__ __launch_bounds__(512) void attn_wo_ln(
    const float* __restrict__ Qb, const float* __restrict__ Ksp,
    const float* __restrict__ Vsp,
    const f16* __restrict__ WoP, const float* __restrict__ bo,
    const f16* __restrict__ Rhi, const f16* __restrict__ Rlo,
    const float* __restrict__ gg, const float* __restrict__ bb_,
    f16* __restrict__ Ohi, f16* __restrict__ Olo,
    const int* __restrict__ alive)
{
  if (alive && *alive == 0) return;
  __shared__ f16 C1[2][64][264];
  __shared__ float red[64][4][2];
  const int tid = threadIdx.x;
  const int m0 = blockIdx.x * 64;
  const int lane = tid & 63, wave = tid >> 6;

  // ---- attention phase (math verbatim from attn_k; loads batched) ----
  {
    const int h = wave & 3;
    const int rbase = (wave >> 2) * 32;
    for (int i = 0; i < 32; i++) {
      const int row_l = rbase + i;
      const long r = m0 + row_l;
      const long qi = r * HD + h * DHD + lane;
      const float qv = Qb[qi];
      float kv[NCc], vv[NCc];
      #pragma unroll
      for (int c = 0; c < NCc; c++) {
        kv[c] = Ksp[((long)c * RR + r) * HD + h * DHD + lane];
        vv[c] = Vsp[((long)c * RR + r) * HD + h * DHD + lane];
      }
      float sc[NCc];
      #pragma unroll
      for (int c = 0; c < NCc; c++) {
        float p = qv * kv[c];
        #pragma unroll
        for (int s = 32; s > 0; s >>= 1) p += __shfl_xor(p, s, 64);
        sc[c] = p * 0.125f;
      }
      float m = sc[0];
      #pragma unroll
      for (int c = 1; c < NCc; c++) m = fmaxf(m, sc[c]);
      float a[NCc];
      float den = 0.f;
      #pragma unroll
      for (int c = 0; c < NCc; c++) { a[c] = expf(sc[c] - m); den += a[c]; }
      float cv = 0.f;
      #pragma unroll
      for (int c = 0; c < NCc; c++) cv = fmaf(a[c] / den, vv[c], cv);
      const f16 hi = (f16)cv;
      C1[0][row_l][h * DHD + lane] = hi;
      C1[1][row_l][h * DHD + lane] = (f16)(cv - (float)hi);
    }
  }
  __syncthreads();

  // ---- Wo GEMM + LN (gemm_ln replica; A-frags from C1) ----
  const int wm = wave & 1, wn = wave >> 1;
  const int lr = lane & 31, lg = lane >> 5;
  f32x16 acc[2];
  #pragma unroll
  for (int nf = 0; nf < 2; nf++)
    #pragma unroll
    for (int g = 0; g < 16; g++) acc[nf][g] = 0.f;

  auto loadB = [&](f16x8 B[2][2][2], int k0) {
    const int kb = (k0 >> 3) + lg;
    #pragma unroll
    for (int kh = 0; kh < 2; kh++)
      #pragma unroll
      for (int nf = 0; nf < 2; nf++)
        #pragma unroll
        for (int hl = 0; hl < 2; hl++)
          B[kh][nf][hl] = *(const f16x8*)(WoP +
              ((long)((wn * 2 + nf) * 32 + kb + kh * 2) * 512 + hl * 256 + lr * 8));
  };
  f16x8 Bc[2][2][2], Bn[2][2][2];
  loadB(Bc, 0);
  #pragma unroll
  for (int s = 0; s < 8; s++) {
    const int k0 = s * 32;
    if (s < 7) loadB((s & 1) ? Bc : Bn, k0 + 32);
    f16x8 fa[2][2];
    #pragma unroll
    for (int kh = 0; kh < 2; kh++)
      #pragma unroll
      for (int hl = 0; hl < 2; hl++)
        fa[kh][hl] = *(const f16x8*)&C1[hl][wm * 32 + lr][k0 + kh * 16 + lg * 8];
    #pragma unroll
    for (int kh = 0; kh < 2; kh++)
      #pragma unroll
      for (int nf = 0; nf < 2; nf++) {
        if (s & 1) { MFMA3(acc[nf], fa[kh][0], fa[kh][1], Bn[kh][nf][0], Bn[kh][nf][1]); }
        else       { MFMA3(acc[nf], fa[kh][0], fa[kh][1], Bc[kh][nf][0], Bc[kh][nf][1]); }
      }
  }

  float pr[16], qr[16];
  #pragma unroll
  for (int g = 0; g < 16; g++) {
    const int row_l = wm * 32 + (g & 3) + 8 * (g >> 2) + 4 * lg;
    const long rbase = (long)(m0 + row_l) * HD;
    float s = 0.f, sq = 0.f;
    #pragma unroll
    for (int nf = 0; nf < 2; nf++) {
      const int col = wn * 64 + nf * 32 + lr;
      float v = acc[nf][g] + bo[col]
              + (float)Rhi[rbase + col] + (float)Rlo[rbase + col];
      acc[nf][g] = v;
      s += v; sq += v * v;
    }
    pr[g] = s; qr[g] = sq;
  }
  #pragma unroll
  for (int g = 0; g < 16; g++)
    #pragma unroll
    for (int i = 1; i <= 16; i <<= 1) {
      pr[g] += __shfl_xor(pr[g], i, 64);
      qr[g] += __shfl_xor(qr[g], i, 64);
    }
  if (lr == 0) {
    #pragma unroll
    for (int g = 0; g < 16; g++) {
      const int row_l = wm * 32 + (g & 3) + 8 * (g >> 2) + 4 * lg;
      red[row_l][wn][0] = pr[g];
      red[row_l][wn][1] = qr[g];
    }
  }
  __syncthreads();
  #pragma unroll
  for (int g = 0; g < 16; g++) {
    const int row_l = wm * 32 + (g & 3) + 8 * (g >> 2) + 4 * lg;
    const float mean = (red[row_l][0][0] + red[row_l][1][0] +
                        red[row_l][2][0] + red[row_l][3][0]) * (1.f / HD);
    const float ex2 = (red[row_l][0][1] + red[row_l][1][1] +
                       red[row_l][2][1] + red[row_l][3][1]) * (1.f / HD);
    const float inv = 1.f / sqrtf(ex2 - mean * mean + 1e-5f);
    const long rbase = (long)(m0 + row_l) * HD;
    #pragma unroll
    for (int nf = 0; nf < 2; nf++) {
      const int col = wn * 64 + nf * 32 + lr;
      const float o = (acc[nf][g] - mean) * inv * gg[col] + bb_[col];
      const f16 hi = (f16)o;
      Ohi[rbase + col] = hi;
      Olo[rbase + col] = (f16)(o - (float)hi);
    }
  }
}

// ---------------------------------------------------------------------------
// FUSED FFN + LN2 + ponder head + ACT. MODE: 0=first, 1=mid, 2=last (cur=1).
// hh lives only in LDS (T1 reuse) — never written to global.
// 512 thr = 8 waves (2 wm x 4 wn); Ws1 GEMM on waves 0-3 (s1_act replica).
// ---------------------------------------------------------------------------
template<int MODE>
__global__ __launch_bounds__(512) void ffn_act(
    const f16* __restrict__ h1hi, const f16* __restrict__ h1lo,
    const f16* __restrict__ Wf1P, const float* __restrict__ bf1,
    const f16* __restrict__ Wf2P, const float* __restrict__ bf2,
    const float* __restrict__ g2, const float* __restrict__ b2,
    const f16* __restrict__ Ws1P, const float* __restrict__ bs1,
    const float* __restrict__ Ws2, const float* __restrict__ bs2,
    const float* __restrict__ psa, const float* __restrict__ psb,
    float* __restrict__ cum, float* __restrict__ rem,
    float* __restrict__ still, float* __restrict__ pc,
    f16* __restrict__ outhi, f16* __restrict__ outlo,
    float* __restrict__ pcdst,
    const int* __restrict__ alive, int* __restrict__ myFlag)
{
  if (MODE != 0 && alive && *alive == 0) return;
  __shared__ f16 H1[2][64][264];
  __shared__ f16 T1[2][64][264];
  __shared__ float red[64][4][2];
  __shared__ float red2[64][2];
  const int tid = threadIdx.x;
  const int m0 = blockIdx.x * 64;
  const int lane = tid & 63, wave = tid >> 6;
  const int wm = wave & 1, wn = wave >> 1;
  const int lr = lane & 31, lg = lane >> 5;

  // cooperative load h1 -> H1
  {
    const int srow = tid >> 3, scg = (tid & 7) * 32;
    const long hb = (long)(m0 + srow) * HD + scg;
    #pragma unroll
    for (int j = 0; j < 4; j++) {
      *(f16x8*)&H1[0][srow][scg + j * 8] = *(const f16x8*)(h1hi + hb + j * 8);
      *(f16x8*)&H1[1][srow][scg + j * 8] = *(const f16x8*)(h1lo + hb + j * 8);
    }
  }
  __syncthreads();

  auto loadBf1 = [&](f16x8 B[2][2][2], int k0, int p) {
    const int kb = (k0 >> 3) + lg;
    #pragma unroll
    for (int kh = 0; kh < 2; kh++)
      #pragma unroll
      for (int nf = 0; nf < 2; nf++)
        #pragma unroll
        for (int hl = 0; hl < 2; hl++)
          B[kh][nf][hl] = *(const f16x8*)(Wf1P +
              ((long)((p * 8 + wn * 2 + nf) * 32 + kb + kh * 2) * 512 + hl * 256 + lr * 8));
  };
  auto loadBf2 = [&](f16x8 B[2][2][2], int k0, int p) {
    const int kb = p * 32 + (k0 >> 3) + lg;
    #pragma unroll
    for (int kh = 0; kh < 2; kh++)
      #pragma unroll
      for (int nf = 0; nf < 2; nf++)
        #pragma unroll
        for (int hl = 0; hl < 2; hl++)
          B[kh][nf][hl] = *(const f16x8*)(Wf2P +
              ((long)((wn * 2 + nf) * 64 + kb + kh * 2) * 512 + hl * 256 + lr * 8));
  };

  f32x16 hacc[2];
  #pragma unroll
  for (int nf = 0; nf < 2; nf++)
    #pragma unroll
    for (int g = 0; g < 16; g++) hacc[nf][g] = 0.f;

  #pragma unroll
  for (int p = 0; p < 2; p++) {
    f32x16 ta[2];
    #pragma unroll
    for (int nf = 0; nf < 2; nf++)
      #pragma unroll
      for (int g = 0; g < 16; g++) ta[nf][g] = 0.f;
    {
      f16x8 Bc[2][2][2], Bn[2][2][2];
      loadBf1(Bc, 0, p);
      #pragma unroll
      for (int s = 0; s < 8; s++) {
        const int k0 = s * 32;
        if (s < 7) loadBf1((s & 1) ? Bc : Bn, k0 + 32, p);
        f16x8 fa[2][2];
        #pragma unroll
        for (int kh = 0; kh < 2; kh++)
          #pragma unroll
          for (int hl = 0; hl < 2; hl++)
            fa[kh][hl] = *(const f16x8*)&H1[hl][wm * 32 + lr][k0 + kh * 16 + lg * 8];
        #pragma unroll
        for (int kh = 0; kh < 2; kh++)
          #pragma unroll
          for (int nf = 0; nf < 2; nf++) {
            if (s & 1) { MFMA3(ta[nf], fa[kh][0], fa[kh][1], Bn[kh][nf][0], Bn[kh][nf][1]); }
            else       { MFMA3(ta[nf], fa[kh][0], fa[kh][1], Bc[kh][nf][0], Bc[kh][nf][1]); }
          }
      }
    }
    __syncthreads();
    #pragma unroll
    for (int nf = 0; nf < 2; nf++) {
      const int col = wn * 64 + nf * 32 + lr;
      const float bb = bf1[p * 256 + col];
      #pragma unroll
      for (int g = 0; g < 16; g++) {
        const int row_l = wm * 32 + (g & 3) + 8 * (g >> 2) + 4 * lg;
        const float v = fmaxf(ta[nf][g] + bb, 0.f);
        const f16 hi = (f16)v;
        T1[0][row_l][col] = hi;
        T1[1][row_l][col] = (f16)(v - (float)hi);
      }
    }
    __syncthreads();
    {
      f16x8 Bc[2][2][2], Bn[2][2][2];
      loadBf2(Bc, 0, p);
      #pragma unroll
      for (int s = 0; s < 8; s++) {
        const int k0 = s * 32;
        if (s < 7) loadBf2((s & 1) ? Bc : Bn, k0 + 32, p);
        f16x8 ft[2][2];
        #pragma unroll
        for (int kh = 0; kh < 2; kh++)
          #pragma unroll
          for (int hl = 0; hl < 2; hl++)
            ft[kh][hl] = *(const f16x8*)&T1[hl][wm * 32 + lr][k0 + kh * 16 + lg * 8];
        #pragma unroll
        for (int kh = 0; kh < 2; kh++)
          #pragma unroll
          for (int nf = 0; nf < 2; nf++) {
            if (s & 1) { MFMA3(hacc[nf], ft[kh][0], ft[kh][1], Bn[kh][nf][0], Bn[kh][nf][1]); }
            else       { MFMA3(hacc[nf], ft[kh][0], ft[kh][1], Bc[kh][nf][0], Bc[kh][nf][1]); }
          }
      }
    }
  }

  // LN2 epilogue
  float pr[16], qr[16];
  #pragma unroll
  for (int g = 0; g < 16; g++) {
    const int row_l = wm * 32 + (g & 3) + 8 * (g >> 2) + 4 * lg;
    float s = 0.f, sq = 0.f;
    #pragma unroll
    for (int nf = 0; nf < 2; nf++) {
      const int col = wn * 64 + nf * 32 + lr;
      float v = hacc[nf][g] + bf2[col]
              + (float)H1[0][row_l][col] + (float)H1[1][row_l][col];
      hacc[nf][g] = v;
      s += v; sq += v * v;
    }
    pr[g] = s; qr[g] = sq;
  }
  #pragma unroll
  for (int g = 0; g < 16; g++)
    #pragma unroll
    for (int i = 1; i <= 16; i <<= 1) {
      pr[g] += __shfl_xor(pr[g], i, 64);
      qr[g] += __shfl_xor(qr[g], i, 64);
    }
  if (lr == 0) {
    #pragma unroll
    for (int g = 0; g < 16; g++) {
      const int row_l = wm * 32 + (g & 3) + 8 * (g >> 2) + 4 * lg;
      red[row_l][wn][0] = pr[g];
      red[row_l][wn][1] = qr[g];
    }
  }
  __syncthreads();   // red ready; all T1 GEMM2 reads done
  #pragma unroll
  for (int g = 0; g < 16; g++) {
    const int row_l = wm * 32 + (g & 3) + 8 * (g >> 2) + 4 * lg;
    const float mean = (red[row_l][0][0] + red[row_l][1][0] +
                        red[row_l][2][0] + red[row_l][3][0]) * (1.f / HD);
    const float ex2 = (red[row_l][0][1] + red[row_l][1][1] +
                       red[row_l][2][1] + red[row_l][3][1]) * (1.f / HD);
    const float inv = 1.f / sqrtf(ex2 - mean * mean + 1e-5f);
    #pragma unroll
    for (int nf = 0; nf < 2; nf++) {
      const int col = wn * 64 + nf * 32 + lr;
      const float o = (hacc[nf][g] - mean) * inv * g2[col] + b2[col];
      const f16 hi = (f16)o;
      T1[0][row_l][col] = hi;             // hh -> LDS only
      T1[1][row_l][col] = (f16)(o - (float)hi);
    }
  }
  __syncthreads();   // hh visible

  // Ws1 GEMM + Ws2 dot (s1_act replica, waves 0-3)
  if (MODE != 2) {
    if (wave < 4) {
      f32x16 sacc[2];
      #pragma unroll
      for (int nf = 0; nf < 2; nf++)
        #pragma unroll
        for (int g = 0; g < 16; g++) sacc[nf][g] = 0.f;
      auto loadBs = [&](f16x8 B[2][2][2], int k0) {
        const int kb = (k0 >> 3) + lg;
        #pragma unroll
        for (int kh = 0; kh < 2; kh++)
          #pragma unroll
          for (int nf = 0; nf < 2; nf++)
            #pragma unroll
            for (int hl = 0; hl < 2; hl++)
              B[kh][nf][hl] = *(const f16x8*)(Ws1P +
                  ((long)((wn * 2 + nf) * 32 + kb + kh * 2) * 512 + hl * 256 + lr * 8));
      };
      f16x8 Bc[2][2][2], Bn[2][2][2];
      loadBs(Bc, 0);
      #pragma unroll
      for (int s = 0; s < 8; s++) {
        const int k0 = s * 32;
        if (s < 7) loadBs((s & 1) ? Bc : Bn, k0 + 32);
        f16x8 fa[2][2];
        #pragma unroll
        for (int kh = 0; kh < 2; kh++)
          #pragma unroll
          for (int hl = 0; hl < 2; hl++)
            fa[kh][hl] = *(const f16x8*)&T1[hl][wm * 32 + lr][k0 + kh * 16 + lg * 8];
        #pragma unroll
        for (int kh = 0; kh < 2; kh++)
          #pragma unroll
          for (int nf = 0; nf < 2; nf++) {
            if (s & 1) { MFMA3(sacc[nf], fa[kh][0], fa[kh][1], Bn[kh][nf][0], Bn[kh][nf][1]); }
            else       { MFMA3(sacc[nf], fa[kh][0], fa[kh][1], Bc[kh][nf][0], Bc[kh][nf][1]); }
          }
      }
      float pr2[16];
      #pragma unroll
      for (int g = 0; g < 16; g++) {
        float s = 0.f;
        #pragma unroll
        for (int nf = 0; nf < 2; nf++) {
          const int col = wn * 64 + nf * 32 + lr;
          const float v = fmaxf(sacc[nf][g] + bs1[col], 0.f);
          s += v * Ws2[col];
        }
        pr2[g] = s;
      }
      #pragma unroll
      for (int g = 0; g < 16; g++)
        #pragma unroll
        for (int i = 1; i <= 16; i <<= 1) pr2[g] += __shfl_xor(pr2[g], i, 64);
      if (lr == 0) {
        #pragma unroll
        for (int g = 0; g < 16; g++) {
          const int row_l = wm * 32 + (g & 3) + 8 * (g >> 2) + 4 * lg;
          red2[row_l][wn] = pr2[g];
        }
      }
    }
  }
  __syncthreads();

  // ACT update (elementwise; curv recomputed identically per thread)
  const float ipsb = 1.f / (psb[0] + 1e-8f);
  const float pa = psa[0], b2v = bs2[0];
  const int colA = tid & 255, rsub = tid >> 8;
  for (int rr = 0; rr < 32; rr++) {
    const int row_l = rr * 2 + rsub;
    const long rg = m0 + row_l;
    float curv;
    if (MODE == 2) curv = 1.f;
    else {
      const float s = red2[row_l][0] + red2[row_l][1] + b2v;
      curv = 1.f / (1.f + expf(-(s - pa) * ipsb));
    }
    const float cu = (MODE == 0) ? 0.f : cum[rg];
    const float re = (MODE == 0) ? 1.f : rem[rg];
    const float st = (MODE == 0) ? 1.f : still[rg];
    const float pp = (MODE == 0) ? 0.f : pc[rg];
    const float cum_n = cu + curv * st;
    float pc_n = pp + st;
    const float still_n = (cum_n < 0.9999f) ? 1.f : 0.f;
    const float wgt = curv * still_n + re * (1.f - still_n);
    const long idx = rg * HD + colA;
    const float prev = (MODE == 0) ? 0.f : ((float)outhi[idx] + (float)outlo[idx]);
    const float hhv = (float)T1[0][row_l][colA] + (float)T1[1][row_l][colA];
    const float newv = prev + hhv * wgt;
    const f16 hi = (f16)newv;
    outhi[idx] = hi;
    outlo[idx] = (f16)(newv - (float)hi);
    const float rem_n = re - curv * still_n;
    pc_n += rem_n * (1.f - still_n);
    if (colA == 0) {
      cum[rg] = cum_n; rem[rg] = rem_n; still[rg] = still_n; pc[rg] = pc_n;
      pcdst[rg] = pc_n;
      if (MODE != 2 && still_n > 0.5f) *myFlag = 1;
    }
  }
}

// ---------------------------------------------------------------------------
// Weight transpose + split into packed frag layout (unchanged).
// ---------------------------------------------------------------------------
__global__ __launch_bounds__(256) void wsplit_k(
    const float* __restrict__ W_in, const float* __restrict__ Wq,
    const float* __restrict__ Wk, const float* __restrict__ Wv,
    const float* __restrict__ Wo, const float* __restrict__ Wf1,
    const float* __restrict__ Wf2, const float* __restrict__ Ws1,
    const float* __restrict__ Wout,
    f16* __restrict__ WinP, f16* __restrict__ WqkvP, f16* __restrict__ WoP,
    f16* __restrict__ Wf1P, f16* __restrict__ Wf2P, f16* __restrict__ Ws1P,
    f16* __restrict__ WoutP)
{
  const int y = blockIdx.y;
  const long idx = (long)blockIdx.x * 256 + threadIdx.x;
  int Npad, Kpad, Ksrc;
  f16* dst;
  switch (y) {
    case 0: Npad = 256; Kpad = 288; Ksrc = 257; dst = WinP;  break;
    case 1: Npad = 768; Kpad = 256; Ksrc = 256; dst = WqkvP; break;
    case 2: Npad = 256; Kpad = 256; Ksrc = 256; dst = WoP;   break;
    case 3: Npad = 512; Kpad = 256; Ksrc = 256; dst = Wf1P;  break;
    case 4: Npad = 256; Kpad = 512; Ksrc = 512; dst = Wf2P;  break;
    case 5: Npad = 128; Kpad = 256; Ksrc = 256; dst = Ws1P;  break;
    default: Npad = 384; Kpad = 256; Ksrc = 256; dst = WoutP; break;
  }
  if (idx >= (long)Npad * Kpad) return;
  const int n = (int)(idx / Kpad), k = (int)(idx % Kpad);
  float v = 0.f;
  if (k < Ksrc) {
    switch (y) {
      case 0: v = W_in[(long)k * 256 + n]; break;
      case 1: { const int sel = n >> 8;
                const float* s = sel == 0 ? Wq : (sel == 1 ? Wk : Wv);
                v = s[(long)k * 256 + (n & 255)]; } break;
      case 2: v = Wo[(long)k * 256 + n]; break;
      case 3: v = Wf1[(long)k * 512 + n]; break;
      case 4: v = Wf2[(long)k * 256 + n]; break;
      case 5: v = Ws1[(long)k * 128 + n]; break;
      default: v = (n < 257) ? Wout[(long)k * 257 + n] : 0.f; break;
    }
  }
  const long base = ((long)(n >> 5) * (Kpad >> 3) + (k >> 3)) * 512 + (n & 31) * 8 + (k & 7);
  const f16 hi = (f16)v;
  dst[base] = hi;
  dst[base + 256] = (f16)(v - (float)hi);
}

__global__ void init_k(int* flags) {
  if (threadIdx.x < 8) flags[threadIdx.x] = 0;
}

// ---------------------------------------------------------------------------
extern "C" void kernel_launch(void* const* d_in, const int* in_sizes, int n_in,
                              void* d_out, int out_size, void* d_ws, size_t ws_size,
                              hipStream_t stream) {
  const float* x    = (const float*)d_in[0];
  const float* W_in = (const float*)d_in[1];
  const float* b_in = (const float*)d_in[2];
  const float* W_out= (const float*)d_in[3];
  const float* b_out= (const float*)d_in[4];
  const float* Wq   = (const float*)d_in[5];
  const float* bq   = (const float*)d_in[6];
  const float* Wk   = (const float*)d_in[7];
  const float* bk   = (const float*)d_in[8];
  const float* Wv   = (const float*)d_in[9];
  const float* bv   = (const float*)d_in[10];
  const float* Wo   = (const float*)d_in[11];
  const float* bo   = (const float*)d_in[12];
  const float* ln1g = (const float*)d_in[13];
  const float* ln1b = (const float*)d_in[14];
  const float* Wf1  = (const float*)d_in[15];
  const float* bf1  = (const float*)d_in[16];
  const float* Wf2  = (const float*)d_in[17];
  const float* bf2  = (const float*)d_in[18];
  const float* ln2g = (const float*)d_in[19];
  const float* ln2b = (const float*)d_in[20];
  const float* Ws1  = (const float*)d_in[21];
  const float* bs1  = (const float*)d_in[22];
  const float* Ws2  = (const float*)d_in[23];
  const float* bs2  = (const float*)d_in[24];
  const float* psa  = (const float*)d_in[25];
  const float* psb  = (const float*)d_in[26];

  float* ws = (float*)d_ws;
  long off = 0;
  auto alloc = [&](long n) { float* p = ws + off; off += n; return p; };
  float* Ks   = alloc((long)CH * RR * HD);
  float* Vs   = alloc((long)CH * RR * HD);
  float* Qb   = alloc((long)RR * HD);
  f16* lin1hi = (f16*)alloc((long)RR * HD / 2);
  f16* lin1lo = (f16*)alloc((long)RR * HD / 2);
  f16* h1hi   = (f16*)alloc((long)RR * HD / 2);
  f16* h1lo   = (f16*)alloc((long)RR * HD / 2);
  f16* outhi  = (f16*)alloc((long)RR * HD / 2);
  f16* outlo  = (f16*)alloc((long)RR * HD / 2);
  f16* WinP   = (f16*)alloc(2 * 256 * 288 / 2);
  f16* WqkvP  = (f16*)alloc(2 * 768 * 256 / 2);
  f16* WoP    = (f16*)alloc(2 * 256 * 256 / 2);
  f16* Wf1P   = (f16*)alloc(2 * 512 * 256 / 2);
  f16* Wf2P   = (f16*)alloc(2 * 256 * 512 / 2);
  f16* Ws1P   = (f16*)alloc(2 * 128 * 256 / 2);
  f16* WoutP  = (f16*)alloc(2 * 384 * 256 / 2);
  float* cum  = alloc(RR);
  float* rem  = alloc(RR);
  float* still= alloc(RR);
  float* pc   = alloc(RR);
  int* flags  = (int*)alloc(8);

  init_k<<<1, 256, 0, stream>>>(flags);
  wsplit_k<<<dim3(768, 7), 256, 0, stream>>>(
      W_in, Wq, Wk, Wv, Wo, Wf1, Wf2, Ws1, W_out,
      WinP, WqkvP, WoP, Wf1P, Wf2P, Ws1P, WoutP);

  float* pcdst = (float*)d_out + (long)RR * FB;

  for (int ci = 0; ci < CH; ci++) {
    const int* al = (ci == 0) ? nullptr : (flags + ci - 1);
    // lin1 + Q/K/V (fused)
    lin1_qkv<<<256, 512, 0, stream>>>(
        x + (long)ci * TT * FB, (long)CH * TT * FB,
        WinP, b_in, WqkvP, bq, bk, bv,
        lin1hi, lin1lo, Qb,
        Ks + (long)ci * RR * HD, Vs + (long)ci * RR * HD, al);
    // attn + Wo + LN1 (fused)
    switch (ci) {
      case 0: attn_wo_ln<1><<<256, 512, 0, stream>>>(Qb, Ks, Vs, WoP, bo, lin1hi, lin1lo, ln1g, ln1b, h1hi, h1lo, al); break;
      case 1: attn_wo_ln<2><<<256, 512, 0, stream>>>(Qb, Ks, Vs, WoP, bo, lin1hi, lin1lo, ln1g, ln1b, h1hi, h1lo, al); break;
      case 2: attn_wo_ln<3><<<256, 512, 0, stream>>>(Qb, Ks, Vs, WoP, bo, lin1hi, lin1lo, ln1g, ln1b, h1hi, h1lo, al); break;
      case 3: attn_wo_ln<4><<<256, 512, 0, stream>>>(Qb, Ks, Vs, WoP, bo, lin1hi, lin1lo, ln1g, ln1b, h1hi, h1lo, al); break;
      case 4: attn_wo_ln<5><<<256, 512, 0, stream>>>(Qb, Ks, Vs, WoP, bo, lin1hi, lin1lo, ln1g, ln1b, h1hi, h1lo, al); break;
      case 5: attn_wo_ln<6><<<256, 512, 0, stream>>>(Qb, Ks, Vs, WoP, bo, lin1hi, lin1lo, ln1g, ln1b, h1hi, h1lo, al); break;
      case 6: attn_wo_ln<7><<<256, 512, 0, stream>>>(Qb, Ks, Vs, WoP, bo, lin1hi, lin1lo, ln1g, ln1b, h1hi, h1lo, al); break;
      default: attn_wo_ln<8><<<256, 512, 0, stream>>>(Qb, Ks, Vs, WoP, bo, lin1hi, lin1lo, ln1g, ln1b, h1hi, h1lo, al); break;
    }
    // FFN + LN2 + ponder + ACT (fused)
    if (ci == 0)
      ffn_act<0><<<256, 512, 0, stream>>>(
          h1hi, h1lo, Wf1P, bf1, Wf2P, bf2, ln2g, ln2b,
          Ws1P, bs1, Ws2, bs2, psa, psb,
          cum, rem, still, pc, outhi, outlo, pcdst, nullptr, flags + 0);
    else if (ci < CH - 1)
      ffn_act<1><<<256, 512, 0, stream>>>(
          h1hi, h1lo, Wf1P, bf1, Wf2P, bf2, ln2g, ln2b,
          Ws1P, bs1, Ws2, bs2, psa, psb,
          cum, rem, still, pc, outhi, outlo, pcdst, al, flags + ci);
    else
      ffn_act<2><<<256, 512, 0, stream>>>(
          h1hi, h1lo, Wf1P, bf1, Wf2P, bf2, ln2g, ln2b,
          Ws1P, bs1, Ws2, bs2, psa, psb,
          cum, rem, still, pc, outhi, outlo, pcdst, al, nullptr);
  }
  // encoder_out = relu(out @ W_out + b_out)
  gemm2<1><<<dim3(128, 6), 256, 0, stream>>>(
      outhi, outlo, HD, WoutP, b_out, (float*)d_out, FB, FB);
}